// Round 1
// baseline (207.965 us; speedup 1.0000x reference)
//
#include <hip/hip_runtime.h>

// MultiLabelSoftMax: B=4096 rows, C=8192 classes, K=8 positives/row.
// out = (1/(B*K)) * sum_{b,k} [ log(exp(p_bk) + sum_neg_b) - p_bk ]
// where sum_neg_b = sum_c exp(pred[b,c]) - sum_k exp(p_bk).
// Memory-bound: 128 MiB predictions read once, coalesced float4.

constexpr int B = 4096;
constexpr int C = 8192;
constexpr int K = 8;
constexpr int BLOCK = 256;                 // 4 waves of 64
constexpr int VEC_PER_THREAD = C / 4 / BLOCK;  // 8 float4 per thread

__global__ __launch_bounds__(BLOCK)
void mlsm_row_kernel(const float* __restrict__ pred,
                     const int* __restrict__ labels,
                     float* __restrict__ out) {
    const int b   = blockIdx.x;
    const int tid = threadIdx.x;
    const float* row = pred + (size_t)b * C;
    const float4* row4 = reinterpret_cast<const float4*>(row);

    // --- full-row sum of exp, strided coalesced float4 loads ---
    float s = 0.0f;
#pragma unroll
    for (int i = 0; i < VEC_PER_THREAD; ++i) {
        float4 v = row4[tid + i * BLOCK];
        s += __expf(v.x) + __expf(v.y) + __expf(v.z) + __expf(v.w);
    }

    // --- wave64 shuffle reduction ---
#pragma unroll
    for (int off = 32; off > 0; off >>= 1)
        s += __shfl_down(s, off, 64);

    __shared__ float wave_sum[BLOCK / 64];
    const int wave = tid >> 6;
    if ((tid & 63) == 0) wave_sum[wave] = s;
    __syncthreads();

    // --- epilogue on thread 0: K=8 positive corrections + loss terms ---
    if (tid == 0) {
        float total = wave_sum[0] + wave_sum[1] + wave_sum[2] + wave_sum[3];

        const int* lab = labels + b * K;
        float pos[K];
        float epos[K];
        float sum_pos = 0.0f;
#pragma unroll
        for (int k = 0; k < K; ++k) {
            pos[k]  = row[lab[k]];
            epos[k] = __expf(pos[k]);
            sum_pos += epos[k];
        }
        const float sum_neg = total - sum_pos;

        float loss = 0.0f;
#pragma unroll
        for (int k = 0; k < K; ++k)
            loss += __logf(epos[k] + sum_neg) - pos[k];

        atomicAdd(out, loss * (1.0f / (float)(B * K)));
    }
}

extern "C" void kernel_launch(void* const* d_in, const int* in_sizes, int n_in,
                              void* d_out, int out_size, void* d_ws, size_t ws_size,
                              hipStream_t stream) {
    const float* pred  = (const float*)d_in[0];
    const int* labels  = (const int*)d_in[1];
    float* out         = (float*)d_out;

    // d_out is poisoned to 0xAA before every launch; zero it (capture-safe).
    hipMemsetAsync(out, 0, sizeof(float), stream);

    mlsm_row_kernel<<<B, BLOCK, 0, stream>>>(pred, labels, out);
}

// Round 2
// 187.167 us; speedup vs baseline: 1.1111x; 1.1111x over previous
//
#include <hip/hip_runtime.h>

// MultiLabelSoftMax: B=4096 rows, C=8192 classes, K=8 positives/row.
// out = (1/(B*K)) * sum_{b,k} [ log(exp(p_bk) + sum_neg_b) - p_bk ]
// where sum_neg_b = sum_c exp(pred[b,c]) - sum_k exp(p_bk).
//
// Structure: kernel1 = one block per row -> partial loss per row in d_ws
//            kernel2 = single block reduces 4096 partials -> d_out scalar.
// No atomics (round-1 suspect: 4096 same-address atomicAdds tail-serialize).

constexpr int B = 4096;
constexpr int C = 8192;
constexpr int K = 8;
constexpr int BLOCK = 256;                 // 4 waves of 64
constexpr int VPT = C / 4 / BLOCK;         // 8 float4 per thread

__global__ __launch_bounds__(BLOCK)
void mlsm_row_kernel(const float* __restrict__ pred,
                     const int* __restrict__ labels,
                     float* __restrict__ partial) {
    const int b   = blockIdx.x;
    const int tid = threadIdx.x;
    const float* row = pred + (size_t)b * C;
    const float4* row4 = reinterpret_cast<const float4*>(row);

    // Prefetch all 8 float4 (32 elems) first: 8 independent loads in flight.
    float4 v[VPT];
#pragma unroll
    for (int i = 0; i < VPT; ++i)
        v[i] = row4[tid + i * BLOCK];

    // 4-way split accumulators for exp ILP.
    float s0 = 0.f, s1 = 0.f, s2 = 0.f, s3 = 0.f;
#pragma unroll
    for (int i = 0; i < VPT; ++i) {
        s0 += __expf(v[i].x);
        s1 += __expf(v[i].y);
        s2 += __expf(v[i].z);
        s3 += __expf(v[i].w);
    }
    float s = (s0 + s1) + (s2 + s3);

    // wave64 shuffle reduction
#pragma unroll
    for (int off = 32; off > 0; off >>= 1)
        s += __shfl_down(s, off, 64);

    __shared__ float wave_sum[BLOCK / 64];
    if ((tid & 63) == 0) wave_sum[tid >> 6] = s;
    __syncthreads();

    // Epilogue on lanes 0..7: one positive each, butterfly over width-8 group.
    if (tid < K) {
        const float total =
            (wave_sum[0] + wave_sum[1]) + (wave_sum[2] + wave_sum[3]);

        const int cls = labels[b * K + tid];
        const float p = row[cls];          // L1/L2 hit (row just streamed)
        const float e = __expf(p);

        float sum_pos = e;
#pragma unroll
        for (int m = 1; m < K; m <<= 1)
            sum_pos += __shfl_xor(sum_pos, m, K);

        const float sum_neg = total - sum_pos;
        float term = __logf(e + sum_neg) - p;
#pragma unroll
        for (int m = 1; m < K; m <<= 1)
            term += __shfl_xor(term, m, K);

        if (tid == 0) partial[b] = term;
    }
}

__global__ __launch_bounds__(BLOCK)
void mlsm_reduce_kernel(const float* __restrict__ partial,
                        float* __restrict__ out) {
    const int tid = threadIdx.x;
    const float4* p4 = reinterpret_cast<const float4*>(partial);

    float s = 0.f;
#pragma unroll
    for (int i = 0; i < B / 4 / BLOCK; ++i) {   // 4 float4 per thread
        float4 v = p4[tid + i * BLOCK];
        s += (v.x + v.y) + (v.z + v.w);
    }
#pragma unroll
    for (int off = 32; off > 0; off >>= 1)
        s += __shfl_down(s, off, 64);

    __shared__ float wave_sum[BLOCK / 64];
    if ((tid & 63) == 0) wave_sum[tid >> 6] = s;
    __syncthreads();

    if (tid == 0)
        out[0] = ((wave_sum[0] + wave_sum[1]) + (wave_sum[2] + wave_sum[3]))
                 * (1.0f / (float)(B * K));
}

extern "C" void kernel_launch(void* const* d_in, const int* in_sizes, int n_in,
                              void* d_out, int out_size, void* d_ws, size_t ws_size,
                              hipStream_t stream) {
    const float* pred = (const float*)d_in[0];
    const int* labels = (const int*)d_in[1];
    float* out        = (float*)d_out;
    float* partial    = (float*)d_ws;       // 4096 floats = 16 KiB

    mlsm_row_kernel<<<B, BLOCK, 0, stream>>>(pred, labels, partial);
    mlsm_reduce_kernel<<<1, BLOCK, 0, stream>>>(partial, out);
}